// Round 1
// baseline (264.292 us; speedup 1.0000x reference)
//
#include <hip/hip_runtime.h>

#define BB 2048
#define FF 256
#define EE 257
#define UU 64
#define HH1 64
#define HH2 32

// SC = log2(e) / sqrt(E): folds softmax temperature into log2-domain for exp2f
#define SC 0.089992807f

// ---------------- K1a: M~ (transposed, scaled) ----------------
// mt[ki*FF + qi] = SC * sum_j (in_w[j*E+qi]+in_b[j]) * (in_w[(E+j)*E+ki]+in_b[E+j])
__global__ __launch_bounds__(256) void k1_mt(const float* __restrict__ in_w,
                                             const float* __restrict__ in_b,
                                             float* __restrict__ mt) {
    const int qi = threadIdx.x;
    const int ki = blockIdx.x;
    float acc = 0.f;
#pragma unroll 4
    for (int j = 0; j < EE; ++j) {
        float aq = in_w[j * EE + qi] + in_b[j];
        float ak = in_w[(EE + j) * EE + ki] + in_b[EE + j];
        acc = fmaf(aq, ak, acc);
    }
    mt[ki * FF + qi] = acc * SC;
}

// ---------------- K1b: vectors u, w, g and scalars alpha, beta, ob ----------------
__global__ __launch_bounds__(256) void k1_vec(const float* __restrict__ in_w,
                                              const float* __restrict__ in_b,
                                              const float* __restrict__ out_w,
                                              const float* __restrict__ out_b,
                                              float* __restrict__ uv, float* __restrict__ wv,
                                              float* __restrict__ gv, float* __restrict__ sc) {
    const int t = threadIdx.x;  // 256
    float au = 0.f, aw = 0.f, ag = 0.f;
#pragma unroll 4
    for (int j = 0; j < EE; ++j) {
        float cq = in_w[j * EE + FF];
        float ck = in_w[(EE + j) * EE + FF];
        float rj = out_w[(EE - 1) * EE + j];
        au = fmaf(in_w[j * EE + t] + in_b[j], ck, au);
        aw = fmaf(cq, in_w[(EE + j) * EE + t] + in_b[EE + j], aw);
        ag = fmaf(in_w[(2 * EE + j) * EE + t] + in_b[2 * EE + j], rj, ag);
    }
    uv[t] = au * SC;
    wv[t] = aw * SC;
    gv[t] = ag;
    if (t < 64) {
        float pa = 0.f, pb = 0.f;
        for (int j = t; j < EE; j += 64) {
            float cq = in_w[j * EE + FF];
            float ck = in_w[(EE + j) * EE + FF];
            float cv = in_w[(2 * EE + j) * EE + FF];
            float rj = out_w[(EE - 1) * EE + j];
            pa = fmaf(cq, ck, pa);
            pb = fmaf(cv, rj, pb);
        }
#pragma unroll
        for (int o = 32; o > 0; o >>= 1) {
            pa += __shfl_down(pa, o, 64);
            pb += __shfl_down(pb, o, 64);
        }
        if (t == 0) {
            sc[0] = pa * SC;      // alpha (scaled, log2 domain)
            sc[1] = pb;           // beta  (value path, unscaled)
            sc[2] = out_b[EE - 1];// ob
        }
    }
}

// ---------------- K2: per-batch attention ----------------
// block: 256 threads = qi; handles 4 batch rows. Single-pass softmax (scores are tiny,
// max-subtraction cancels mathematically).
__global__ __launch_bounds__(256) void k2_attn(const float* __restrict__ x,
                                               const float* __restrict__ mt,
                                               const float* __restrict__ uv,
                                               const float* __restrict__ wv,
                                               const float* __restrict__ gv,
                                               const float* __restrict__ sc,
                                               float* __restrict__ xa) {
    const int qi = threadIdx.x;
    const int b0 = blockIdx.x * 4;
    __shared__ float xs[4][FF];
    __shared__ float ts[4][FF];
#pragma unroll
    for (int i = 0; i < 4; ++i) xs[i][qi] = x[(b0 + i) * FF + qi];
    const float alpha_s = sc[0], beta = sc[1], ob = sc[2];
    const float gq = gv[qi];
    __syncthreads();
#pragma unroll
    for (int i = 0; i < 4; ++i) ts[i][qi] = fmaf(beta, xs[i][qi], gq);  // t[b,ki] hoisted
    const float uq = uv[qi];
    float xq[4], a[4], le[4], acc[4];
#pragma unroll
    for (int i = 0; i < 4; ++i) {
        xq[i] = xs[i][qi];
        a[i] = fmaf(alpha_s, xq[i], uq);
        le[i] = 0.f;
        acc[i] = 0.f;
    }
    __syncthreads();
#pragma unroll 2
    for (int ki = 0; ki < FF; ++ki) {
        const float mtv = mt[ki * FF + qi];
        const float wk = wv[ki];
#pragma unroll
        for (int i = 0; i < 4; ++i) {
            float xk = xs[i][ki];
            float s = fmaf(xk, a[i], fmaf(wk, xq[i], mtv));  // log2-domain score
            float e = exp2f(s);
            le[i] += e;
            acc[i] = fmaf(e, ts[i][ki], acc[i]);
        }
    }
#pragma unroll
    for (int i = 0; i < 4; ++i) xa[(b0 + i) * FF + qi] = acc[i] / le[i] + ob;
}

// ---------------- K3: per-feature MLPs ----------------
// block: one feature f, 256 batch elements (thread = b). Weights via block-uniform
// (scalarizable) loads. No runtime-indexed register arrays.
__global__ __launch_bounds__(256) void k3_fnn(const float* xa_in,  // NOT restrict: aliases fo
                                              const float* __restrict__ w1,
                                              const float* __restrict__ b1,
                                              const float* __restrict__ w2,
                                              const float* __restrict__ b2,
                                              const float* __restrict__ w3,
                                              const float* __restrict__ b3,
                                              const float* __restrict__ w4,
                                              const float* __restrict__ b4,
                                              float* __restrict__ fo) {
    const int f = blockIdx.x >> 3;
    const int b = ((blockIdx.x & 7) << 8) | threadIdx.x;
    const float xv = xa_in[b * FF + f];
    const float* w1f = w1 + f * UU;
    const float* b1f = b1 + f * UU;
    const float* w2f = w2 + f * (UU * HH1);
    const float* b2f = b2 + f * HH1;
    const float* w3f = w3 + f * (HH1 * HH2);
    const float* b3f = b3 + f * HH2;
    const float* w4f = w4 + f * HH2;

    float h2v[HH1];
#pragma unroll
    for (int j = 0; j < HH1; ++j) h2v[j] = b2f[j];

    // phase 1: h2 += relu(xv*w1[u]+b1[u]) * w2[u][:]   (u rolled -> no h1 array)
    for (int u = 0; u < UU; ++u) {
        float h1u = fmaxf(fmaf(xv, w1f[u], b1f[u]), 0.f);
        const float* wr = w2f + u * HH1;
#pragma unroll
        for (int j = 0; j < HH1; ++j) h2v[j] = fmaf(h1u, wr[j], h2v[j]);
    }

    // phase 2: fully unrolled (static indexing on both register arrays)
    float h3v[HH2];
#pragma unroll
    for (int g = 0; g < HH2; ++g) h3v[g] = b3f[g];
#pragma unroll
    for (int u = 0; u < HH1; ++u) {
        float h = fmaxf(h2v[u], 0.f);
#pragma unroll
        for (int g = 0; g < HH2; ++g) h3v[g] = fmaf(h, w3f[u * HH2 + g], h3v[g]);
    }

    float acc = b4[f];
#pragma unroll
    for (int g = 0; g < HH2; ++g) acc = fmaf(fmaxf(h3v[g], 0.f), w4f[g], acc);

    fo[b * FF + f] = acc;
}

// ---------------- K4: out[b] = sum_f fo[b,f] + bias ----------------
__global__ __launch_bounds__(64) void k4_sum(const float* __restrict__ fo,
                                             const float* __restrict__ bias,
                                             float* __restrict__ out) {
    const int b = blockIdx.x;
    const int t = threadIdx.x;  // 64
    const float* r = fo + b * FF;
    float s = r[t] + r[t + 64] + r[t + 128] + r[t + 192];
#pragma unroll
    for (int o = 32; o > 0; o >>= 1) s += __shfl_down(s, o, 64);
    if (t == 0) out[b] = s + bias[0];
}

extern "C" void kernel_launch(void* const* d_in, const int* in_sizes, int n_in,
                              void* d_out, int out_size, void* d_ws, size_t ws_size,
                              hipStream_t stream) {
    const float* x    = (const float*)d_in[0];
    const float* w1   = (const float*)d_in[1];
    const float* b1   = (const float*)d_in[2];
    const float* w2   = (const float*)d_in[3];
    const float* b2   = (const float*)d_in[4];
    const float* w3   = (const float*)d_in[5];
    const float* b3   = (const float*)d_in[6];
    const float* w4   = (const float*)d_in[7];
    const float* b4   = (const float*)d_in[8];
    const float* in_w = (const float*)d_in[9];
    const float* in_b = (const float*)d_in[10];
    const float* out_w= (const float*)d_in[11];
    const float* out_b= (const float*)d_in[12];
    const float* bias = (const float*)d_in[13];

    float* out = (float*)d_out;       // [B]
    float* fo  = out + BB;            // [B,F] — also used as xa buffer (bijective per-thread read->write)
    float* ws  = (float*)d_ws;
    float* mt  = ws;                  // 65536
    float* uvp = ws + 65536;          // 256
    float* wvp = ws + 65792;          // 256
    float* gvp = ws + 66048;          // 256
    float* scp = ws + 66304;          // 8

    k1_mt <<<FF, 256, 0, stream>>>(in_w, in_b, mt);
    k1_vec<<<1, 256, 0, stream>>>(in_w, in_b, out_w, out_b, uvp, wvp, gvp, scp);
    k2_attn<<<BB / 4, 256, 0, stream>>>(x, mt, uvp, wvp, gvp, scp, fo);
    k3_fnn<<<FF * (BB / 256), 256, 0, stream>>>(fo, w1, b1, w2, b2, w3, b3, w4, b4, fo);
    k4_sum<<<BB, 64, 0, stream>>>(fo, bias, out);
}

// Round 2
// 189.586 us; speedup vs baseline: 1.3940x; 1.3940x over previous
//
#include <hip/hip_runtime.h>

#define BB 2048
#define FF 256
#define EE 257
#define UU 64
#define HH1 64
#define HH2 32

// SC = log2(e) / sqrt(E): folds softmax temperature into log2-domain for exp2f
#define SC 0.089992807f

// ---------------- K1a: M~ (transposed, scaled) ----------------
// mt[ki*FF + qi] = SC * sum_j (in_w[j*E+qi]+in_b[j]) * (in_w[(E+j)*E+ki]+in_b[E+j])
__global__ __launch_bounds__(256) void k1_mt(const float* __restrict__ in_w,
                                             const float* __restrict__ in_b,
                                             float* __restrict__ mt) {
    const int qi = threadIdx.x;
    const int ki = blockIdx.x;
    float acc = 0.f;
#pragma unroll 8
    for (int j = 0; j < EE; ++j) {
        float aq = in_w[j * EE + qi] + in_b[j];
        float ak = in_w[(EE + j) * EE + ki] + in_b[EE + j];
        acc = fmaf(aq, ak, acc);
    }
    mt[ki * FF + qi] = acc * SC;
}

// ---------------- K1b: vectors u, w, g and scalars alpha, beta, ob ----------------
__global__ __launch_bounds__(256) void k1_vec(const float* __restrict__ in_w,
                                              const float* __restrict__ in_b,
                                              const float* __restrict__ out_w,
                                              const float* __restrict__ out_b,
                                              float* __restrict__ uv, float* __restrict__ wv,
                                              float* __restrict__ gv, float* __restrict__ sc) {
    const int t = threadIdx.x;  // 256
    float au = 0.f, aw = 0.f, ag = 0.f;
#pragma unroll 4
    for (int j = 0; j < EE; ++j) {
        float cq = in_w[j * EE + FF];
        float ck = in_w[(EE + j) * EE + FF];
        float rj = out_w[(EE - 1) * EE + j];
        au = fmaf(in_w[j * EE + t] + in_b[j], ck, au);
        aw = fmaf(cq, in_w[(EE + j) * EE + t] + in_b[EE + j], aw);
        ag = fmaf(in_w[(2 * EE + j) * EE + t] + in_b[2 * EE + j], rj, ag);
    }
    uv[t] = au * SC;
    wv[t] = aw * SC;
    gv[t] = ag;
    if (t < 64) {
        float pa = 0.f, pb = 0.f;
        for (int j = t; j < EE; j += 64) {
            float cq = in_w[j * EE + FF];
            float ck = in_w[(EE + j) * EE + FF];
            float cv = in_w[(2 * EE + j) * EE + FF];
            float rj = out_w[(EE - 1) * EE + j];
            pa = fmaf(cq, ck, pa);
            pb = fmaf(cv, rj, pb);
        }
#pragma unroll
        for (int o = 32; o > 0; o >>= 1) {
            pa += __shfl_down(pa, o, 64);
            pb += __shfl_down(pb, o, 64);
        }
        if (t == 0) {
            sc[0] = pa * SC;      // alpha (scaled, log2 domain)
            sc[1] = pb;           // beta  (value path, unscaled)
            sc[2] = out_b[EE - 1];// ob
        }
    }
}

// ---------------- K2: per-batch attention (LDS-free) ----------------
// block: 256 threads = qi; 4 batch rows. All ki-indexed streams (x-row, wv, gv) are
// wave-uniform -> scalar loads; the value term is split acc = acc1 + beta*acc2 so
// every VALU fma has <=1 SGPR operand. No LDS, no __syncthreads.
__global__ __launch_bounds__(256) void k2_attn(const float* __restrict__ x,
                                               const float* __restrict__ mt,
                                               const float* __restrict__ uv,
                                               const float* __restrict__ wv,
                                               const float* __restrict__ gv,
                                               const float* __restrict__ sc,
                                               float* __restrict__ xa) {
    const int qi = threadIdx.x;
    const int b0 = blockIdx.x * 4;
    const float alpha_s = sc[0], beta = sc[1], ob = sc[2];
    const float uq = uv[qi];
    float xq[4], a[4], le[4], ac1[4], ac2[4];
#pragma unroll
    for (int i = 0; i < 4; ++i) {
        xq[i] = x[(b0 + i) * FF + qi];
        a[i]  = fmaf(alpha_s, xq[i], uq);
        le[i] = 0.f; ac1[i] = 0.f; ac2[i] = 0.f;
    }
#pragma unroll 8
    for (int ki = 0; ki < FF; ++ki) {
        const float mtv = mt[ki * FF + qi];   // coalesced vector load
        const float wk  = wv[ki];             // uniform -> scalar
        const float gk  = gv[ki];             // uniform -> scalar
#pragma unroll
        for (int i = 0; i < 4; ++i) {
            const float xk = x[(b0 + i) * FF + ki];  // uniform -> scalar
            float s = fmaf(xk, a[i], fmaf(wk, xq[i], mtv));  // log2-domain score
            float e = exp2f(s);
            le[i]  += e;
            ac1[i]  = fmaf(e, gk, ac1[i]);
            ac2[i]  = fmaf(e, xk, ac2[i]);
        }
    }
#pragma unroll
    for (int i = 0; i < 4; ++i)
        xa[(b0 + i) * FF + qi] = (ac1[i] + beta * ac2[i]) / le[i] + ob;
}

// ---------------- K3: per-feature MLPs ----------------
// XCD-friendly mapping: same-feature rep-blocks are 256 apart in blockIdx
// (256 % 8 == 0 -> all land on the same XCD's L2; each XCD touches only the
// 32 features == xcd (mod 8): 768 KB of weights, L2-resident).
__global__ __launch_bounds__(256) void k3_fnn(const float* xa_in,  // NOT restrict: aliases fo
                                              const float* __restrict__ w1,
                                              const float* __restrict__ b1,
                                              const float* __restrict__ w2,
                                              const float* __restrict__ b2,
                                              const float* __restrict__ w3,
                                              const float* __restrict__ b3,
                                              const float* __restrict__ w4,
                                              const float* __restrict__ b4,
                                              float* __restrict__ fo) {
    const int f = blockIdx.x & 255;
    const int b = ((blockIdx.x >> 8) << 8) | threadIdx.x;
    const float xv = xa_in[b * FF + f];
    const float* w1f = w1 + f * UU;
    const float* b1f = b1 + f * UU;
    const float* w2f = w2 + f * (UU * HH1);
    const float* b2f = b2 + f * HH1;
    const float* w3f = w3 + f * (HH1 * HH2);
    const float* b3f = b3 + f * HH2;
    const float* w4f = w4 + f * HH2;

    float h2v[HH1];
#pragma unroll
    for (int j = 0; j < HH1; ++j) h2v[j] = b2f[j];

    // phase 1: h2 += relu(xv*w1[u]+b1[u]) * w2[u][:]   (u rolled -> no h1 array)
    for (int u = 0; u < UU; ++u) {
        float h1u = fmaxf(fmaf(xv, w1f[u], b1f[u]), 0.f);
        const float* wr = w2f + u * HH1;
#pragma unroll
        for (int j = 0; j < HH1; ++j) h2v[j] = fmaf(h1u, wr[j], h2v[j]);
    }

    // phase 2: fully unrolled (static indexing on both register arrays)
    float h3v[HH2];
#pragma unroll
    for (int g = 0; g < HH2; ++g) h3v[g] = b3f[g];
#pragma unroll
    for (int u = 0; u < HH1; ++u) {
        float h = fmaxf(h2v[u], 0.f);
#pragma unroll
        for (int g = 0; g < HH2; ++g) h3v[g] = fmaf(h, w3f[u * HH2 + g], h3v[g]);
    }

    float acc = b4[f];
#pragma unroll
    for (int g = 0; g < HH2; ++g) acc = fmaf(fmaxf(h3v[g], 0.f), w4f[g], acc);

    fo[b * FF + f] = acc;
}

// ---------------- K4: out[b] = sum_f fo[b,f] + bias ----------------
__global__ __launch_bounds__(64) void k4_sum(const float* __restrict__ fo,
                                             const float* __restrict__ bias,
                                             float* __restrict__ out) {
    const int b = blockIdx.x;
    const int t = threadIdx.x;  // 64
    const float* r = fo + b * FF;
    float s = r[t] + r[t + 64] + r[t + 128] + r[t + 192];
#pragma unroll
    for (int o = 32; o > 0; o >>= 1) s += __shfl_down(s, o, 64);
    if (t == 0) out[b] = s + bias[0];
}

extern "C" void kernel_launch(void* const* d_in, const int* in_sizes, int n_in,
                              void* d_out, int out_size, void* d_ws, size_t ws_size,
                              hipStream_t stream) {
    const float* x    = (const float*)d_in[0];
    const float* w1   = (const float*)d_in[1];
    const float* b1   = (const float*)d_in[2];
    const float* w2   = (const float*)d_in[3];
    const float* b2   = (const float*)d_in[4];
    const float* w3   = (const float*)d_in[5];
    const float* b3   = (const float*)d_in[6];
    const float* w4   = (const float*)d_in[7];
    const float* b4   = (const float*)d_in[8];
    const float* in_w = (const float*)d_in[9];
    const float* in_b = (const float*)d_in[10];
    const float* out_w= (const float*)d_in[11];
    const float* out_b= (const float*)d_in[12];
    const float* bias = (const float*)d_in[13];

    float* out = (float*)d_out;       // [B]
    float* fo  = out + BB;            // [B,F] — also used as xa buffer (bijective per-thread read->write)
    float* ws  = (float*)d_ws;
    float* mt  = ws;                  // 65536
    float* uvp = ws + 65536;          // 256
    float* wvp = ws + 65792;          // 256
    float* gvp = ws + 66048;          // 256
    float* scp = ws + 66304;          // 8

    k1_mt <<<FF, 256, 0, stream>>>(in_w, in_b, mt);
    k1_vec<<<1, 256, 0, stream>>>(in_w, in_b, out_w, out_b, uvp, wvp, gvp, scp);
    k2_attn<<<BB / 4, 256, 0, stream>>>(x, mt, uvp, wvp, gvp, scp, fo);
    k3_fnn<<<FF * (BB / 256), 256, 0, stream>>>(fo, w1, b1, w2, b2, w3, b3, w4, b4, fo);
    k4_sum<<<BB, 64, 0, stream>>>(fo, bias, out);
}

// Round 3
// 175.715 us; speedup vs baseline: 1.5041x; 1.0789x over previous
//
#include <hip/hip_runtime.h>

#define BB 2048
#define FF 256
#define EE 257
#define UU 64
#define HH1 64
#define HH2 32

// SC = log2(e) / sqrt(E): folds softmax temperature into log2-domain for exp2f
#define SC 0.089992807f

// ---------------- K1a: M~ (transposed, scaled) ----------------
__global__ __launch_bounds__(256) void k1_mt(const float* __restrict__ in_w,
                                             const float* __restrict__ in_b,
                                             float* __restrict__ mt) {
    const int qi = threadIdx.x;
    const int ki = blockIdx.x;
    float acc = 0.f;
#pragma unroll 8
    for (int j = 0; j < EE; ++j) {
        float aq = in_w[j * EE + qi] + in_b[j];
        float ak = in_w[(EE + j) * EE + ki] + in_b[EE + j];
        acc = fmaf(aq, ak, acc);
    }
    mt[ki * FF + qi] = acc * SC;
}

// ---------------- K1b: vectors u, w, g and scalars alpha, beta, ob ----------------
__global__ __launch_bounds__(256) void k1_vec(const float* __restrict__ in_w,
                                              const float* __restrict__ in_b,
                                              const float* __restrict__ out_w,
                                              const float* __restrict__ out_b,
                                              float* __restrict__ uv, float* __restrict__ wv,
                                              float* __restrict__ gv, float* __restrict__ sc) {
    const int t = threadIdx.x;  // 256
    float au = 0.f, aw = 0.f, ag = 0.f;
#pragma unroll 8
    for (int j = 0; j < EE; ++j) {
        float cq = in_w[j * EE + FF];
        float ck = in_w[(EE + j) * EE + FF];
        float rj = out_w[(EE - 1) * EE + j];
        au = fmaf(in_w[j * EE + t] + in_b[j], ck, au);
        aw = fmaf(cq, in_w[(EE + j) * EE + t] + in_b[EE + j], aw);
        ag = fmaf(in_w[(2 * EE + j) * EE + t] + in_b[2 * EE + j], rj, ag);
    }
    uv[t] = au * SC;
    wv[t] = aw * SC;
    gv[t] = ag;
    if (t < 64) {
        float pa = 0.f, pb = 0.f;
        for (int j = t; j < EE; j += 64) {
            float cq = in_w[j * EE + FF];
            float ck = in_w[(EE + j) * EE + FF];
            float cv = in_w[(2 * EE + j) * EE + FF];
            float rj = out_w[(EE - 1) * EE + j];
            pa = fmaf(cq, ck, pa);
            pb = fmaf(cv, rj, pb);
        }
#pragma unroll
        for (int o = 32; o > 0; o >>= 1) {
            pa += __shfl_down(pa, o, 64);
            pb += __shfl_down(pb, o, 64);
        }
        if (t == 0) {
            sc[0] = pa * SC;      // alpha (scaled, log2 domain)
            sc[1] = pb;           // beta  (value path, unscaled)
            sc[2] = out_b[EE - 1];// ob
        }
    }
}

// ---------------- K2: per-batch attention (LDS-free) ----------------
__global__ __launch_bounds__(256) void k2_attn(const float* __restrict__ x,
                                               const float* __restrict__ mt,
                                               const float* __restrict__ uv,
                                               const float* __restrict__ wv,
                                               const float* __restrict__ gv,
                                               const float* __restrict__ sc,
                                               float* __restrict__ xa) {
    const int qi = threadIdx.x;
    const int b0 = blockIdx.x * 4;
    const float alpha_s = sc[0], beta = sc[1], ob = sc[2];
    const float uq = uv[qi];
    float xq[4], a[4], le[4], ac1[4], ac2[4];
#pragma unroll
    for (int i = 0; i < 4; ++i) {
        xq[i] = x[(b0 + i) * FF + qi];
        a[i]  = fmaf(alpha_s, xq[i], uq);
        le[i] = 0.f; ac1[i] = 0.f; ac2[i] = 0.f;
    }
#pragma unroll 8
    for (int ki = 0; ki < FF; ++ki) {
        const float mtv = mt[ki * FF + qi];   // coalesced vector load
        const float wk  = wv[ki];             // uniform -> scalar
        const float gk  = gv[ki];             // uniform -> scalar
#pragma unroll
        for (int i = 0; i < 4; ++i) {
            const float xk = x[(b0 + i) * FF + ki];  // uniform -> scalar
            float s = fmaf(xk, a[i], fmaf(wk, xq[i], mtv));  // log2-domain score
            float e = exp2f(s);
            le[i]  += e;
            ac1[i]  = fmaf(e, gk, ac1[i]);
            ac2[i]  = fmaf(e, xk, ac2[i]);
        }
    }
#pragma unroll
    for (int i = 0; i < 4; ++i)
        xa[(b0 + i) * FF + qi] = (ac1[i] + beta * ac2[i]) / le[i] + ob;
}

// ---------------- K3: per-feature MLPs, 4 batch rows per thread ----------------
// Each block-uniform weight load now feeds 4 FMAs (load:FMA = 1:4). H1 chunked
// into 16-wide slices so all register arrays stay statically indexed:
//   acc[4][16] (64 VGPR) per chunk, h3[4][32] (128 VGPR) accumulated across chunks.
// XCD mapping: f = blk&255, same-f rep-blocks 256 apart -> same XCD L2.
__global__ __launch_bounds__(256, 2) void k3_fnn(const float* xa_in,  // NOT restrict: aliases fo
                                                 const float* __restrict__ w1,
                                                 const float* __restrict__ b1,
                                                 const float* __restrict__ w2,
                                                 const float* __restrict__ b2,
                                                 const float* __restrict__ w3,
                                                 const float* __restrict__ b3,
                                                 const float* __restrict__ w4,
                                                 const float* __restrict__ b4,
                                                 float* __restrict__ fo) {
    const int f  = blockIdx.x & 255;
    const int b0 = ((blockIdx.x >> 8) << 10) | (threadIdx.x << 2);  // rep*1024 + tid*4
    const float* w1f = w1 + f * UU;
    const float* b1f = b1 + f * UU;
    const float* w2f = w2 + f * (UU * HH1);
    const float* b2f = b2 + f * HH1;
    const float* w3f = w3 + f * (HH1 * HH2);
    const float* b3f = b3 + f * HH2;
    const float* w4f = w4 + f * HH2;

    float xv[4];
#pragma unroll
    for (int r = 0; r < 4; ++r) xv[r] = xa_in[(b0 + r) * FF + f];

    float h3[4][HH2];
#pragma unroll
    for (int g = 0; g < HH2; ++g) {
        const float bg = b3f[g];
#pragma unroll
        for (int r = 0; r < 4; ++r) h3[r][g] = bg;
    }

    for (int jc = 0; jc < HH1; jc += 16) {   // rolled: 4 chunks
        float acc[4][16];
#pragma unroll
        for (int jj = 0; jj < 16; ++jj) {
            const float bj = b2f[jc + jj];
#pragma unroll
            for (int r = 0; r < 4; ++r) acc[r][jj] = bj;
        }
#pragma unroll 4
        for (int u = 0; u < UU; ++u) {
            const float w1u = w1f[u];
            const float b1u = b1f[u];
            float h1[4];
#pragma unroll
            for (int r = 0; r < 4; ++r) h1[r] = fmaxf(fmaf(xv[r], w1u, b1u), 0.f);
            const float* wr = w2f + u * HH1 + jc;
#pragma unroll
            for (int jj = 0; jj < 16; ++jj) {
                const float w2v = wr[jj];
#pragma unroll
                for (int r = 0; r < 4; ++r) acc[r][jj] = fmaf(h1[r], w2v, acc[r][jj]);
            }
        }
        // consume chunk into h3
#pragma unroll
        for (int jj = 0; jj < 16; ++jj) {
            float h[4];
#pragma unroll
            for (int r = 0; r < 4; ++r) h[r] = fmaxf(acc[r][jj], 0.f);
            const float* w3r = w3f + (jc + jj) * HH2;
#pragma unroll
            for (int g = 0; g < HH2; ++g) {
                const float w3v = w3r[g];
#pragma unroll
                for (int r = 0; r < 4; ++r) h3[r][g] = fmaf(h[r], w3v, h3[r][g]);
            }
        }
    }

    float o[4];
    const float b4v = b4[f];
#pragma unroll
    for (int r = 0; r < 4; ++r) o[r] = b4v;
#pragma unroll
    for (int g = 0; g < HH2; ++g) {
        const float w4v = w4f[g];
#pragma unroll
        for (int r = 0; r < 4; ++r) o[r] = fmaf(fmaxf(h3[r][g], 0.f), w4v, o[r]);
    }
#pragma unroll
    for (int r = 0; r < 4; ++r) fo[(b0 + r) * FF + f] = o[r];
}

// ---------------- K4: out[b] = sum_f fo[b,f] + bias ----------------
__global__ __launch_bounds__(64) void k4_sum(const float* __restrict__ fo,
                                             const float* __restrict__ bias,
                                             float* __restrict__ out) {
    const int b = blockIdx.x;
    const int t = threadIdx.x;  // 64
    const float* r = fo + b * FF;
    float s = r[t] + r[t + 64] + r[t + 128] + r[t + 192];
#pragma unroll
    for (int o = 32; o > 0; o >>= 1) s += __shfl_down(s, o, 64);
    if (t == 0) out[b] = s + bias[0];
}

extern "C" void kernel_launch(void* const* d_in, const int* in_sizes, int n_in,
                              void* d_out, int out_size, void* d_ws, size_t ws_size,
                              hipStream_t stream) {
    const float* x    = (const float*)d_in[0];
    const float* w1   = (const float*)d_in[1];
    const float* b1   = (const float*)d_in[2];
    const float* w2   = (const float*)d_in[3];
    const float* b2   = (const float*)d_in[4];
    const float* w3   = (const float*)d_in[5];
    const float* b3   = (const float*)d_in[6];
    const float* w4   = (const float*)d_in[7];
    const float* b4   = (const float*)d_in[8];
    const float* in_w = (const float*)d_in[9];
    const float* in_b = (const float*)d_in[10];
    const float* out_w= (const float*)d_in[11];
    const float* out_b= (const float*)d_in[12];
    const float* bias = (const float*)d_in[13];

    float* out = (float*)d_out;       // [B]
    float* fo  = out + BB;            // [B,F] — also used as xa buffer (bijective per-thread read->write)
    float* ws  = (float*)d_ws;
    float* mt  = ws;                  // 65536
    float* uvp = ws + 65536;          // 256
    float* wvp = ws + 65792;          // 256
    float* gvp = ws + 66048;          // 256
    float* scp = ws + 66304;          // 8

    k1_mt <<<FF, 256, 0, stream>>>(in_w, in_b, mt);
    k1_vec<<<1, 256, 0, stream>>>(in_w, in_b, out_w, out_b, uvp, wvp, gvp, scp);
    k2_attn<<<BB / 4, 256, 0, stream>>>(x, mt, uvp, wvp, gvp, scp, fo);
    k3_fnn<<<FF * (BB / 1024), 256, 0, stream>>>(fo, w1, b1, w2, b2, w3, b3, w4, b4, fo);
    k4_sum<<<BB, 64, 0, stream>>>(fo, bias, out);
}

// Round 4
// 140.801 us; speedup vs baseline: 1.8771x; 1.2480x over previous
//
#include <hip/hip_runtime.h>

#define BB 2048
#define FF 256
#define EE 257
#define UU 64
#define HH1 64
#define HH2 32

// SC = log2(e) / sqrt(E): folds softmax temperature into log2-domain for exp2f
#define SC 0.089992807f

typedef __attribute__((ext_vector_type(8))) short short8;   // 8 bf16 (4 VGPR)
typedef __attribute__((ext_vector_type(4))) float f32x4;    // MFMA acc

__device__ inline short f2bf(float x) {                     // RNE f32 -> bf16 bits
    unsigned u = __builtin_bit_cast(unsigned, x);
    unsigned r = (u + 0x7FFFu + ((u >> 16) & 1u)) >> 16;
    return (short)r;
}
__device__ inline float bf2f(short s) {
    unsigned u = ((unsigned)(unsigned short)s) << 16;
    return __builtin_bit_cast(float, u);
}
__device__ inline f32x4 splat4(float v) { f32x4 r; r[0]=v; r[1]=v; r[2]=v; r[3]=v; return r; }

// ---------------- K1a: M~ (transposed, scaled) ----------------
__global__ __launch_bounds__(256) void k1_mt(const float* __restrict__ in_w,
                                             const float* __restrict__ in_b,
                                             float* __restrict__ mt) {
    const int qi = threadIdx.x;
    const int ki = blockIdx.x;
    float acc = 0.f;
#pragma unroll 16
    for (int j = 0; j < EE; ++j) {
        float aq = in_w[j * EE + qi] + in_b[j];
        float ak = in_w[(EE + j) * EE + ki] + in_b[EE + j];
        acc = fmaf(aq, ak, acc);
    }
    mt[ki * FF + qi] = acc * SC;
}

// ---------------- K1b: vectors u, w, g and scalars alpha, beta, ob ----------------
__global__ __launch_bounds__(256) void k1_vec(const float* __restrict__ in_w,
                                              const float* __restrict__ in_b,
                                              const float* __restrict__ out_w,
                                              const float* __restrict__ out_b,
                                              float* __restrict__ uv, float* __restrict__ wv,
                                              float* __restrict__ gv, float* __restrict__ sc) {
    const int t = threadIdx.x;  // 256
    float au = 0.f, aw = 0.f, ag = 0.f;
#pragma unroll 8
    for (int j = 0; j < EE; ++j) {
        float cq = in_w[j * EE + FF];
        float ck = in_w[(EE + j) * EE + FF];
        float rj = out_w[(EE - 1) * EE + j];
        au = fmaf(in_w[j * EE + t] + in_b[j], ck, au);
        aw = fmaf(cq, in_w[(EE + j) * EE + t] + in_b[EE + j], aw);
        ag = fmaf(in_w[(2 * EE + j) * EE + t] + in_b[2 * EE + j], rj, ag);
    }
    uv[t] = au * SC;
    wv[t] = aw * SC;
    gv[t] = ag;
    if (t < 64) {
        float pa = 0.f, pb = 0.f;
        for (int j = t; j < EE; j += 64) {
            float cq = in_w[j * EE + FF];
            float ck = in_w[(EE + j) * EE + FF];
            float cv = in_w[(2 * EE + j) * EE + FF];
            float rj = out_w[(EE - 1) * EE + j];
            pa = fmaf(cq, ck, pa);
            pb = fmaf(cv, rj, pb);
        }
#pragma unroll
        for (int o = 32; o > 0; o >>= 1) {
            pa += __shfl_down(pa, o, 64);
            pb += __shfl_down(pb, o, 64);
        }
        if (t == 0) {
            sc[0] = pa * SC;      // alpha (scaled, log2 domain)
            sc[1] = pb;           // beta  (value path, unscaled)
            sc[2] = out_b[EE - 1];// ob
        }
    }
}

// ---------------- K2: per-batch attention (LDS-free) ----------------
__global__ __launch_bounds__(256) void k2_attn(const float* __restrict__ x,
                                               const float* __restrict__ mt,
                                               const float* __restrict__ uv,
                                               const float* __restrict__ wv,
                                               const float* __restrict__ gv,
                                               const float* __restrict__ sc,
                                               float* __restrict__ xa) {
    const int qi = threadIdx.x;
    const int b0 = blockIdx.x * 4;
    const float alpha_s = sc[0], beta = sc[1], ob = sc[2];
    const float uq = uv[qi];
    float xq[4], a[4], le[4], ac1[4], ac2[4];
#pragma unroll
    for (int i = 0; i < 4; ++i) {
        xq[i] = x[(b0 + i) * FF + qi];
        a[i]  = fmaf(alpha_s, xq[i], uq);
        le[i] = 0.f; ac1[i] = 0.f; ac2[i] = 0.f;
    }
#pragma unroll 8
    for (int ki = 0; ki < FF; ++ki) {
        const float mtv = mt[ki * FF + qi];   // coalesced vector load
        const float wk  = wv[ki];             // uniform -> scalar
        const float gk  = gv[ki];             // uniform -> scalar
#pragma unroll
        for (int i = 0; i < 4; ++i) {
            const float xk = x[(b0 + i) * FF + ki];  // uniform -> scalar
            float s = fmaf(xk, a[i], fmaf(wk, xq[i], mtv));  // log2-domain score
            float e = exp2f(s);
            le[i]  += e;
            ac1[i]  = fmaf(e, gk, ac1[i]);
            ac2[i]  = fmaf(e, xk, ac2[i]);
        }
    }
#pragma unroll
    for (int i = 0; i < 4; ++i)
        xa[(b0 + i) * FF + qi] = (ac1[i] + beta * ac2[i]) / le[i] + ob;
}

// ---------------- K3: per-feature MLPs via split-bf16 MFMA ----------------
// Block = (feature f, row-half). 4 waves x 256 rows, wave-private, barrier-free.
// Layer2 computed transposed (h2T = w2T * h1T): B-frag (h1) built in-register;
// D gives h-contiguous packs -> b64 LDS writes. Layer3 standard (h3 = h2 * w3).
// Split bf16: P ~= Ah*Bh + Ah*Bl + Al*Bh (drop lo*lo), rel err ~2^-17.
__global__ __launch_bounds__(256, 2) void k3_fnn(const float* xa_in,  // aliases fo
                                                 const float* __restrict__ w1,
                                                 const float* __restrict__ b1,
                                                 const float* __restrict__ w2,
                                                 const float* __restrict__ b2,
                                                 const float* __restrict__ w3,
                                                 const float* __restrict__ b3,
                                                 const float* __restrict__ w4,
                                                 const float* __restrict__ b4,
                                                 float* fo) {
    const int f     = blockIdx.x & 255;
    const int rhalf = blockIdx.x >> 8;         // 0/1 (same-f blocks 256 apart -> same XCD)
    const int tid   = threadIdx.x;
    const int wvid  = tid >> 6;                // wave 0..3
    const int l     = tid & 63;
    const int lr    = l & 15;
    const int lq    = l >> 4;

    const float* w1f = w1 + f * UU;
    const float* b1f = b1 + f * UU;
    const float* w2f = w2 + f * (UU * HH1);
    const float* b2f = b2 + f * HH1;
    const float* w3f = w3 + f * (HH1 * HH2);
    const float* b3f = b3 + f * HH2;
    const float* w4f = w4 + f * HH2;
    const float  b4v = b4[f];

    // ---- preload weight fragments (once per block, reused for 1024 rows) ----
    // w2T A-frag: lane: row=h=ht*16+lr, k=u=kb*32+lq*8+j  -> w2[u][h]
    short8 W2h[4][2], W2l[4][2];
#pragma unroll
    for (int ht = 0; ht < 4; ++ht)
#pragma unroll
        for (int kb = 0; kb < 2; ++kb)
#pragma unroll
            for (int j = 0; j < 8; ++j) {
                float t = w2f[(kb * 32 + lq * 8 + j) * HH1 + ht * 16 + lr];
                short h = f2bf(t);
                W2h[ht][kb][j] = h;
                W2l[ht][kb][j] = f2bf(t - bf2f(h));
            }
    // w3 B-frag: lane: col=g=ct*16+lr, k=h=kb*32+lq*8+j -> w3[h][g]
    short8 W3h[2][2], W3l[2][2];
#pragma unroll
    for (int ct = 0; ct < 2; ++ct)
#pragma unroll
        for (int kb = 0; kb < 2; ++kb)
#pragma unroll
            for (int j = 0; j < 8; ++j) {
                float t = w3f[(kb * 32 + lq * 8 + j) * HH2 + ct * 16 + lr];
                short h = f2bf(t);
                W3h[ct][kb][j] = h;
                W3l[ct][kb][j] = f2bf(t - bf2f(h));
            }
    // biases / w4, per-lane
    f32x4 B2[4];
#pragma unroll
    for (int ht = 0; ht < 4; ++ht)
#pragma unroll
        for (int r = 0; r < 4; ++r) B2[ht][r] = b2f[ht * 16 + lq * 4 + r];  // b2 indexed by h (D row)
    const float B3s0 = b3f[lr], B3s1 = b3f[16 + lr];                        // b3 indexed by g (D col)
    const float w4v0 = w4f[lr], w4v1 = w4f[16 + lr];
    // w1/b1 per-lane: u = kb*32 + lq*8 + j (chunk-invariant)
    float W1v[2][8], B1v[2][8];
#pragma unroll
    for (int kb = 0; kb < 2; ++kb)
#pragma unroll
        for (int j = 0; j < 8; ++j) {
            W1v[kb][j] = w1f[kb * 32 + lq * 8 + j];
            B1v[kb][j] = b1f[kb * 32 + lq * 8 + j];
        }

    // wave-private h2 staging: [wave][row 0..31][h 0..63] bf16 hi/lo, XOR-swizzled
    __shared__ __align__(16) short lds_hi[4][32][64];
    __shared__ __align__(16) short lds_lo[4][32][64];

    const int rows_w = rhalf * 1024 + wvid * 256;
    for (int ch = 0; ch < 8; ++ch) {
        const int rows0 = rows_w + ch * 32;

        // ---- layer1: build h1T B-frags directly in registers ----
        // B-frag: lane: col=row_b=rbt*16+lr, k=u=kb*32+lq*8+j -> h1[row_b][u]
        short8 Bh[2][2], Bl[2][2];
#pragma unroll
        for (int rbt = 0; rbt < 2; ++rbt) {
            const float xv = xa_in[(rows0 + rbt * 16 + lr) * FF + f];
#pragma unroll
            for (int kb = 0; kb < 2; ++kb)
#pragma unroll
                for (int j = 0; j < 8; ++j) {
                    float h = fmaxf(fmaf(xv, W1v[kb][j], B1v[kb][j]), 0.f);
                    short hh = f2bf(h);
                    Bh[rbt][kb][j] = hh;
                    Bl[rbt][kb][j] = f2bf(h - bf2f(hh));
                }
        }

        // ---- layer2T: h2T = w2T * h1T ; relu+split -> LDS ----
#pragma unroll
        for (int rbt = 0; rbt < 2; ++rbt) {
            const int row = rbt * 16 + lr;       // D col = row_b local
            const int swz = (row & 7) << 3;
#pragma unroll
            for (int ht = 0; ht < 4; ++ht) {
                f32x4 acc = B2[ht];
#pragma unroll
                for (int kb = 0; kb < 2; ++kb) {
                    acc = __builtin_amdgcn_mfma_f32_16x16x32_bf16(W2h[ht][kb], Bh[rbt][kb], acc, 0, 0, 0);
                    acc = __builtin_amdgcn_mfma_f32_16x16x32_bf16(W2h[ht][kb], Bl[rbt][kb], acc, 0, 0, 0);
                    acc = __builtin_amdgcn_mfma_f32_16x16x32_bf16(W2l[ht][kb], Bh[rbt][kb], acc, 0, 0, 0);
                }
                float v0 = fmaxf(acc[0], 0.f), v1 = fmaxf(acc[1], 0.f);
                float v2 = fmaxf(acc[2], 0.f), v3 = fmaxf(acc[3], 0.f);
                short h0 = f2bf(v0), h1 = f2bf(v1), h2 = f2bf(v2), h3 = f2bf(v3);
                short l0 = f2bf(v0 - bf2f(h0)), l1 = f2bf(v1 - bf2f(h1));
                short l2 = f2bf(v2 - bf2f(h2)), l3 = f2bf(v3 - bf2f(h3));
                unsigned dh0 = (unsigned)(unsigned short)h0 | ((unsigned)(unsigned short)h1 << 16);
                unsigned dh1 = (unsigned)(unsigned short)h2 | ((unsigned)(unsigned short)h3 << 16);
                unsigned dl0 = (unsigned)(unsigned short)l0 | ((unsigned)(unsigned short)l1 << 16);
                unsigned dl1 = (unsigned)(unsigned short)l2 | ((unsigned)(unsigned short)l3 << 16);
                const int hb = (ht * 16 + lq * 4) ^ swz;   // lane holds h = ht*16+lq*4+r (contig 4)
                *(unsigned long long*)&lds_hi[wvid][row][hb] =
                    (unsigned long long)dh0 | ((unsigned long long)dh1 << 32);
                *(unsigned long long*)&lds_lo[wvid][row][hb] =
                    (unsigned long long)dl0 | ((unsigned long long)dl1 << 32);
            }
        }
        // wave-private LDS: same-wave write->read, compiler inserts lgkmcnt; no barrier.

        // ---- layer3: h3 = h2 * w3 ; relu ; dot w4 ; shfl-reduce ----
#pragma unroll
        for (int rbt = 0; rbt < 2; ++rbt) {
            const int row = rbt * 16 + lr;       // A row = row_b local
            const int swz = (row & 7) << 3;
            short8 Ah[2], Al[2];
#pragma unroll
            for (int kb = 0; kb < 2; ++kb) {
                const int hb = (kb * 32 + lq * 8) ^ swz;
                Ah[kb] = *(const short8*)&lds_hi[wvid][row][hb];
                Al[kb] = *(const short8*)&lds_lo[wvid][row][hb];
            }
            f32x4 a0 = splat4(B3s0);
            f32x4 a1 = splat4(B3s1);
#pragma unroll
            for (int kb = 0; kb < 2; ++kb) {
                a0 = __builtin_amdgcn_mfma_f32_16x16x32_bf16(Ah[kb], W3h[0][kb], a0, 0, 0, 0);
                a0 = __builtin_amdgcn_mfma_f32_16x16x32_bf16(Ah[kb], W3l[0][kb], a0, 0, 0, 0);
                a0 = __builtin_amdgcn_mfma_f32_16x16x32_bf16(Al[kb], W3h[0][kb], a0, 0, 0, 0);
                a1 = __builtin_amdgcn_mfma_f32_16x16x32_bf16(Ah[kb], W3h[1][kb], a1, 0, 0, 0);
                a1 = __builtin_amdgcn_mfma_f32_16x16x32_bf16(Ah[kb], W3l[1][kb], a1, 0, 0, 0);
                a1 = __builtin_amdgcn_mfma_f32_16x16x32_bf16(Al[kb], W3h[1][kb], a1, 0, 0, 0);
            }
            float sr0 = fmaf(fmaxf(a0[0], 0.f), w4v0, fmaxf(a1[0], 0.f) * w4v1);
            float sr1 = fmaf(fmaxf(a0[1], 0.f), w4v0, fmaxf(a1[1], 0.f) * w4v1);
            float sr2 = fmaf(fmaxf(a0[2], 0.f), w4v0, fmaxf(a1[2], 0.f) * w4v1);
            float sr3 = fmaf(fmaxf(a0[3], 0.f), w4v0, fmaxf(a1[3], 0.f) * w4v1);
#pragma unroll
            for (int m = 1; m < 16; m <<= 1) {
                sr0 += __shfl_xor(sr0, m, 64);
                sr1 += __shfl_xor(sr1, m, 64);
                sr2 += __shfl_xor(sr2, m, 64);
                sr3 += __shfl_xor(sr3, m, 64);
            }
            if (lr == 0) {
                const int rb = rows0 + rbt * 16 + lq * 4;
                fo[(rb + 0) * FF + f] = sr0 + b4v;
                fo[(rb + 1) * FF + f] = sr1 + b4v;
                fo[(rb + 2) * FF + f] = sr2 + b4v;
                fo[(rb + 3) * FF + f] = sr3 + b4v;
            }
        }
    }
}

// ---------------- K4: out[b] = sum_f fo[b,f] + bias ----------------
__global__ __launch_bounds__(64) void k4_sum(const float* __restrict__ fo,
                                             const float* __restrict__ bias,
                                             float* __restrict__ out) {
    const int b = blockIdx.x;
    const int t = threadIdx.x;  // 64
    const float* r = fo + b * FF;
    float s = r[t] + r[t + 64] + r[t + 128] + r[t + 192];
#pragma unroll
    for (int o = 32; o > 0; o >>= 1) s += __shfl_down(s, o, 64);
    if (t == 0) out[b] = s + bias[0];
}

extern "C" void kernel_launch(void* const* d_in, const int* in_sizes, int n_in,
                              void* d_out, int out_size, void* d_ws, size_t ws_size,
                              hipStream_t stream) {
    const float* x    = (const float*)d_in[0];
    const float* w1   = (const float*)d_in[1];
    const float* b1   = (const float*)d_in[2];
    const float* w2   = (const float*)d_in[3];
    const float* b2   = (const float*)d_in[4];
    const float* w3   = (const float*)d_in[5];
    const float* b3   = (const float*)d_in[6];
    const float* w4   = (const float*)d_in[7];
    const float* b4   = (const float*)d_in[8];
    const float* in_w = (const float*)d_in[9];
    const float* in_b = (const float*)d_in[10];
    const float* out_w= (const float*)d_in[11];
    const float* out_b= (const float*)d_in[12];
    const float* bias = (const float*)d_in[13];

    float* out = (float*)d_out;       // [B]
    float* fo  = out + BB;            // [B,F] — also used as xa buffer
    float* ws  = (float*)d_ws;
    float* mt  = ws;                  // 65536
    float* uvp = ws + 65536;          // 256
    float* wvp = ws + 65792;          // 256
    float* gvp = ws + 66048;          // 256
    float* scp = ws + 66304;          // 8

    k1_mt <<<FF, 256, 0, stream>>>(in_w, in_b, mt);
    k1_vec<<<1, 256, 0, stream>>>(in_w, in_b, out_w, out_b, uvp, wvp, gvp, scp);
    k2_attn<<<BB / 4, 256, 0, stream>>>(x, mt, uvp, wvp, gvp, scp, fo);
    k3_fnn<<<FF * (BB / 1024), 256, 0, stream>>>(fo, w1, b1, w2, b2, w3, b3, w4, b4, fo);
    k4_sum<<<BB, 64, 0, stream>>>(fo, bias, out);
}